// Round 1
// baseline (1513.320 us; speedup 1.0000x reference)
//
#include <hip/hip_runtime.h>

#define B_ROWS 1024
#define F_FLD  160000
#define D_DIM  16
#define CHUNK  500
#define NCHUNK (F_FLD / CHUNK)   // 320

// Pass 1: c[f] = bias[f] - 0.5 * sum_d emb[f][d]^2 ; also zero the accumulators.
__global__ __launch_bounds__(256) void fm_prep(const float* __restrict__ emb,
                                               const float* __restrict__ bias,
                                               float* __restrict__ c,
                                               float* __restrict__ acc) {
    int i = blockIdx.x * 256 + threadIdx.x;
    if (i < F_FLD) {
        const float4* e = (const float4*)(emb + (size_t)i * D_DIM);
        float4 e0 = e[0], e1 = e[1], e2 = e[2], e3 = e[3];
        float s = e0.x*e0.x + e0.y*e0.y + e0.z*e0.z + e0.w*e0.w
                + e1.x*e1.x + e1.y*e1.y + e1.z*e1.z + e1.w*e1.w
                + e2.x*e2.x + e2.y*e2.y + e2.z*e2.z + e2.w*e2.w
                + e3.x*e3.x + e3.y*e3.y + e3.z*e3.z + e3.w*e3.w;
        c[i] = bias[i] - 0.5f * s;
    }
    if (i < B_ROWS * (D_DIM + 1)) acc[i] = 0.0f;   // ws is poisoned 0xAA every call
}

// Pass 2: lanes <-> rows. Each thread owns one row over a 500-field chunk.
// emb/c addresses are wave-uniform (broadcast / scalar loads); x is streamed
// per-lane as int4 (full 64B-line consumption via L1 over 4 iterations).
__global__ __launch_bounds__(256) void fm_main(const int* __restrict__ x,
                                               const float* __restrict__ emb,
                                               const float* __restrict__ c,
                                               float* __restrict__ acc) {
    const int row = blockIdx.y * 256 + threadIdx.x;        // 0..1023
    const int f0  = blockIdx.x * CHUNK;
    const int* xp = x + (size_t)row * F_FLD + f0;

    float ev[D_DIM];
#pragma unroll
    for (int d = 0; d < D_DIM; ++d) ev[d] = 0.0f;
    float cacc = 0.0f;

    for (int i = 0; i < CHUNK; i += 4) {
        int4 xv = *(const int4*)(xp + i);
        const float* eb = emb + (size_t)(f0 + i) * D_DIM;
        const float* cb = c + f0 + i;
#pragma unroll
        for (int j = 0; j < 4; ++j) {
            int xs = (j == 0) ? xv.x : (j == 1) ? xv.y : (j == 2) ? xv.z : xv.w;
            float m = (xs > 0) ? 1.0f : 0.0f;
            const float4* e = (const float4*)(eb + j * D_DIM);
            float4 e0 = e[0], e1 = e[1], e2 = e[2], e3 = e[3];
            ev[0]  += m * e0.x;  ev[1]  += m * e0.y;
            ev[2]  += m * e0.z;  ev[3]  += m * e0.w;
            ev[4]  += m * e1.x;  ev[5]  += m * e1.y;
            ev[6]  += m * e1.z;  ev[7]  += m * e1.w;
            ev[8]  += m * e2.x;  ev[9]  += m * e2.y;
            ev[10] += m * e2.z;  ev[11] += m * e2.w;
            ev[12] += m * e3.x;  ev[13] += m * e3.y;
            ev[14] += m * e3.z;  ev[15] += m * e3.w;
            cacc   += m * cb[j];
        }
    }

    float* dst = acc + (size_t)row * D_DIM;
#pragma unroll
    for (int d = 0; d < D_DIM; ++d) atomicAdd(dst + d, ev[d]);
    atomicAdd(acc + (size_t)B_ROWS * D_DIM + row, cacc);
}

// Pass 3: out[b] = g_bias + cacc[b] + 0.5 * ||ev[b]||^2
__global__ __launch_bounds__(256) void fm_final(const float* __restrict__ acc,
                                                const float* __restrict__ g_bias,
                                                float* __restrict__ out) {
    int row = blockIdx.x * 256 + threadIdx.x;
    if (row >= B_ROWS) return;
    const float4* e = (const float4*)(acc + (size_t)row * D_DIM);
    float4 e0 = e[0], e1 = e[1], e2 = e[2], e3 = e[3];
    float s = e0.x*e0.x + e0.y*e0.y + e0.z*e0.z + e0.w*e0.w
            + e1.x*e1.x + e1.y*e1.y + e1.z*e1.z + e1.w*e1.w
            + e2.x*e2.x + e2.y*e2.y + e2.z*e2.z + e2.w*e2.w
            + e3.x*e3.x + e3.y*e3.y + e3.z*e3.z + e3.w*e3.w;
    out[row] = g_bias[0] + acc[(size_t)B_ROWS * D_DIM + row] + 0.5f * s;
}

extern "C" void kernel_launch(void* const* d_in, const int* in_sizes, int n_in,
                              void* d_out, int out_size, void* d_ws, size_t ws_size,
                              hipStream_t stream) {
    const int*   x      = (const int*)d_in[0];
    const float* emb_w  = (const float*)d_in[1];
    const float* bias_w = (const float*)d_in[2];
    const float* g_bias = (const float*)d_in[3];
    float*       out    = (float*)d_out;

    // workspace layout: c[F] (640000 B) | acc[B*17] (69632 B)
    float* c   = (float*)d_ws;
    float* acc = (float*)((char*)d_ws + (size_t)F_FLD * sizeof(float));

    fm_prep<<<dim3((F_FLD + 255) / 256), dim3(256), 0, stream>>>(emb_w, bias_w, c, acc);
    fm_main<<<dim3(NCHUNK, B_ROWS / 256), dim3(256), 0, stream>>>(x, emb_w, c, acc);
    fm_final<<<dim3((B_ROWS + 255) / 256), dim3(256), 0, stream>>>(acc, g_bias, out);
}

// Round 2
// 1345.063 us; speedup vs baseline: 1.1251x; 1.1251x over previous
//
#include <hip/hip_runtime.h>

#define B_ROWS 1024
#define F_FLD  160000
#define D_DIM  16
#define TILE   64
#define TPB    10               // tiles per block -> 640 columns per block
#define CHUNK  (TILE * TPB)     // 640
#define NCHUNK (F_FLD / CHUNK)  // 250

// Pass 1: c[f] = bias[f] - 0.5 * ||emb[f]||^2 ; zero the accumulators.
__global__ __launch_bounds__(256) void fm_prep(const float* __restrict__ emb,
                                               const float* __restrict__ bias,
                                               float* __restrict__ c,
                                               float* __restrict__ acc) {
    int i = blockIdx.x * 256 + threadIdx.x;
    if (i < F_FLD) {
        const float4* e = (const float4*)(emb + (size_t)i * D_DIM);
        float4 e0 = e[0], e1 = e[1], e2 = e[2], e3 = e[3];
        float s = e0.x*e0.x + e0.y*e0.y + e0.z*e0.z + e0.w*e0.w
                + e1.x*e1.x + e1.y*e1.y + e1.z*e1.z + e1.w*e1.w
                + e2.x*e2.x + e2.y*e2.y + e2.z*e2.z + e2.w*e2.w
                + e3.x*e3.x + e3.y*e3.y + e3.z*e3.z + e3.w*e3.w;
        c[i] = bias[i] - 0.5f * s;
    }
    if (i < B_ROWS * (D_DIM + 1)) acc[i] = 0.0f;   // ws is poisoned 0xAA every call
}

// Pass 2: coalesced x streaming. Each wave reads 64 consecutive ints of one
// row (256B, one transaction, line fully consumed immediately), __ballot
// compresses to a 64-bit column mask in LDS (2KB). Compute: thread t owns
// row t, 64-column inner loop, wave-uniform emb/c loads (scalar cache).
__global__ __launch_bounds__(256) void fm_main(const int* __restrict__ x,
                                               const float* __restrict__ emb,
                                               const float* __restrict__ c,
                                               float* __restrict__ acc) {
    __shared__ unsigned long long msk[256];
    const int tid  = threadIdx.x;
    const int wave = tid >> 6;
    const int lane = tid & 63;
    const int rowbase = blockIdx.y * 256;
    const int f0 = blockIdx.x * CHUNK;

    float ev[D_DIM];
#pragma unroll
    for (int d = 0; d < D_DIM; ++d) ev[d] = 0.0f;
    float cacc = 0.0f;

    for (int t = 0; t < TPB; ++t) {
        const int c0 = f0 + t * TILE;
        // --- stage: wave `wave` produces masks for rows wave*64 .. wave*64+63
        const int* xp = x + (size_t)(rowbase + wave * 64) * F_FLD + c0 + lane;
#pragma unroll 8
        for (int i = 0; i < 64; ++i) {
            int xv = xp[(size_t)i * F_FLD];
            unsigned long long m = __ballot(xv > 0);
            if (lane == 0) msk[wave * 64 + i] = m;
        }
        __syncthreads();
        // --- compute: thread t handles row (rowbase + t) over 64 columns
        unsigned long long m = msk[tid];
        const float* eb = emb + (size_t)c0 * D_DIM;
        const float* cb = c + c0;
#pragma unroll 4
        for (int j = 0; j < TILE; ++j) {
            float mm = ((m >> j) & 1ull) ? 1.0f : 0.0f;
            const float4* e = (const float4*)(eb + (size_t)j * D_DIM);
            float4 e0 = e[0], e1 = e[1], e2 = e[2], e3 = e[3];
            ev[0]  += mm * e0.x;  ev[1]  += mm * e0.y;
            ev[2]  += mm * e0.z;  ev[3]  += mm * e0.w;
            ev[4]  += mm * e1.x;  ev[5]  += mm * e1.y;
            ev[6]  += mm * e1.z;  ev[7]  += mm * e1.w;
            ev[8]  += mm * e2.x;  ev[9]  += mm * e2.y;
            ev[10] += mm * e2.z;  ev[11] += mm * e2.w;
            ev[12] += mm * e3.x;  ev[13] += mm * e3.y;
            ev[14] += mm * e3.z;  ev[15] += mm * e3.w;
            cacc   += mm * cb[j];
        }
        __syncthreads();
    }

    float* dst = acc + (size_t)(rowbase + tid) * D_DIM;
#pragma unroll
    for (int d = 0; d < D_DIM; ++d) atomicAdd(dst + d, ev[d]);
    atomicAdd(acc + (size_t)B_ROWS * D_DIM + rowbase + tid, cacc);
}

// Pass 3: out[b] = g_bias + cacc[b] + 0.5 * ||ev[b]||^2
__global__ __launch_bounds__(256) void fm_final(const float* __restrict__ acc,
                                                const float* __restrict__ g_bias,
                                                float* __restrict__ out) {
    int row = blockIdx.x * 256 + threadIdx.x;
    if (row >= B_ROWS) return;
    const float4* e = (const float4*)(acc + (size_t)row * D_DIM);
    float4 e0 = e[0], e1 = e[1], e2 = e[2], e3 = e[3];
    float s = e0.x*e0.x + e0.y*e0.y + e0.z*e0.z + e0.w*e0.w
            + e1.x*e1.x + e1.y*e1.y + e1.z*e1.z + e1.w*e1.w
            + e2.x*e2.x + e2.y*e2.y + e2.z*e2.z + e2.w*e2.w
            + e3.x*e3.x + e3.y*e3.y + e3.z*e3.z + e3.w*e3.w;
    out[row] = g_bias[0] + acc[(size_t)B_ROWS * D_DIM + row] + 0.5f * s;
}

extern "C" void kernel_launch(void* const* d_in, const int* in_sizes, int n_in,
                              void* d_out, int out_size, void* d_ws, size_t ws_size,
                              hipStream_t stream) {
    const int*   x      = (const int*)d_in[0];
    const float* emb_w  = (const float*)d_in[1];
    const float* bias_w = (const float*)d_in[2];
    const float* g_bias = (const float*)d_in[3];
    float*       out    = (float*)d_out;

    // workspace layout: c[F] (640000 B) | acc[B*17] (69632 B)
    float* c   = (float*)d_ws;
    float* acc = (float*)((char*)d_ws + (size_t)F_FLD * sizeof(float));

    fm_prep<<<dim3((F_FLD + 255) / 256), dim3(256), 0, stream>>>(emb_w, bias_w, c, acc);
    fm_main<<<dim3(NCHUNK, B_ROWS / 256), dim3(256), 0, stream>>>(x, emb_w, c, acc);
    fm_final<<<dim3((B_ROWS + 255) / 256), dim3(256), 0, stream>>>(acc, g_bias, out);
}

// Round 3
// 929.961 us; speedup vs baseline: 1.6273x; 1.4464x over previous
//
#include <hip/hip_runtime.h>

#define B_ROWS 1024
#define F_FLD  160000
#define D_DIM  16
#define TCOLS  256               // columns per block (64 lanes x int4)
#define NCHUNK (F_FLD / TCOLS)   // 625
#define NSTAT  (D_DIM + 1)       // 16 ev components + cacc
#define ACC_N  (B_ROWS * NSTAT)  // 17408, layout [17][1024] (plane-major)
#define RED_SLAB 25              // chunks per reduce block (625 = 25*25)

// Pass 1: c[f] = bias[f] - 0.5 * ||emb[f]||^2 ; zero acc planes.
__global__ __launch_bounds__(256) void fm_prep(const float* __restrict__ emb,
                                               const float* __restrict__ bias,
                                               float* __restrict__ c,
                                               float* __restrict__ acc) {
    int i = blockIdx.x * 256 + threadIdx.x;
    if (i < F_FLD) {
        const float4* e = (const float4*)(emb + (size_t)i * D_DIM);
        float4 e0 = e[0], e1 = e[1], e2 = e[2], e3 = e[3];
        float s = e0.x*e0.x + e0.y*e0.y + e0.z*e0.z + e0.w*e0.w
                + e1.x*e1.x + e1.y*e1.y + e1.z*e1.z + e1.w*e1.w
                + e2.x*e2.x + e2.y*e2.y + e2.z*e2.z + e2.w*e2.w
                + e3.x*e3.x + e3.y*e3.y + e3.z*e3.z + e3.w*e3.w;
        c[i] = bias[i] - 0.5f * s;
    }
    if (i < ACC_N) acc[i] = 0.0f;   // ws is poisoned 0xAA every call
}

// Pass 2: each block = 256 rows x 256 cols of x. Wave w stages rows w*64..+63:
// lane loads int4 (wave moves 1KB/instr, line consumed immediately), 4 ballots
// compress 256 cols -> 4x64-bit masks in LDS [4][256] (8KB, conflict-free
// b64 reads). Compute: thread t owns row t, 256-col loop, wave-uniform emb/c
// (scalar loads). Tail: coalesced partial writes (or atomic fallback).
__global__ __launch_bounds__(256) void fm_main(const int* __restrict__ x,
                                               const float* __restrict__ emb,
                                               const float* __restrict__ c,
                                               float* __restrict__ partial,
                                               float* __restrict__ acc,
                                               int use_partial) {
    __shared__ unsigned long long msk[4][256];
    const int tid  = threadIdx.x;
    const int wave = tid >> 6;
    const int lane = tid & 63;
    const int rowbase = blockIdx.y * 256;
    const int c0 = blockIdx.x * TCOLS;

    // ---- stage: 64 rows per wave, batched 8 deep (8KB in flight per wave)
    {
        const int4* xp = (const int4*)(x + (size_t)(rowbase + wave * 64) * F_FLD + c0)
                         + lane;
        const size_t rstride = F_FLD / 4;   // int4s per row
        for (int i = 0; i < 64; i += 8) {
            int4 v[8];
#pragma unroll
            for (int k = 0; k < 8; ++k) v[k] = xp[(size_t)(i + k) * rstride];
#pragma unroll
            for (int k = 0; k < 8; ++k) {
                unsigned long long m0 = __ballot(v[k].x > 0);
                unsigned long long m1 = __ballot(v[k].y > 0);
                unsigned long long m2 = __ballot(v[k].z > 0);
                unsigned long long m3 = __ballot(v[k].w > 0);
                if (lane == 0) {
                    int r = wave * 64 + i + k;
                    msk[0][r] = m0; msk[1][r] = m1; msk[2][r] = m2; msk[3][r] = m3;
                }
            }
        }
    }
    __syncthreads();

    // ---- compute: thread t = row rowbase+t; col = 4*l + j, bit l of msk[j]
    unsigned long long m0 = msk[0][tid], m1 = msk[1][tid],
                       m2 = msk[2][tid], m3 = msk[3][tid];
    float ev[D_DIM];
#pragma unroll
    for (int d = 0; d < D_DIM; ++d) ev[d] = 0.0f;
    float cacc = 0.0f;

    const float* eb = emb + (size_t)c0 * D_DIM;
    const float* cb = c + c0;
#pragma unroll 4
    for (int l = 0; l < 64; ++l) {
#pragma unroll
        for (int j = 0; j < 4; ++j) {
            float mm = (((j == 0 ? m0 : j == 1 ? m1 : j == 2 ? m2 : m3) >> l) & 1ull)
                           ? 1.0f : 0.0f;
            const float4* e = (const float4*)(eb + (size_t)(4 * l + j) * D_DIM);
            float4 e0 = e[0], e1 = e[1], e2 = e[2], e3 = e[3];
            ev[0]  += mm * e0.x;  ev[1]  += mm * e0.y;
            ev[2]  += mm * e0.z;  ev[3]  += mm * e0.w;
            ev[4]  += mm * e1.x;  ev[5]  += mm * e1.y;
            ev[6]  += mm * e1.z;  ev[7]  += mm * e1.w;
            ev[8]  += mm * e2.x;  ev[9]  += mm * e2.y;
            ev[10] += mm * e2.z;  ev[11] += mm * e2.w;
            ev[12] += mm * e3.x;  ev[13] += mm * e3.y;
            ev[14] += mm * e3.z;  ev[15] += mm * e3.w;
            cacc   += mm * cb[4 * l + j];
        }
    }

    const int row = rowbase + tid;
    if (use_partial) {
        // partial[chunk][plane d (0..16)][row] — every store wave-coalesced 1KB
        float* p = partial + (size_t)blockIdx.x * ACC_N + row;
#pragma unroll
        for (int d = 0; d < D_DIM; ++d) p[d * B_ROWS] = ev[d];
        p[D_DIM * B_ROWS] = cacc;
    } else {
#pragma unroll
        for (int d = 0; d < D_DIM; ++d) atomicAdd(acc + d * B_ROWS + row, ev[d]);
        atomicAdd(acc + D_DIM * B_ROWS + row, cacc);
    }
}

// Pass 2b: fold 625 chunk-partials into acc[17][1024].
__global__ __launch_bounds__(256) void fm_reduce(const float* __restrict__ partial,
                                                 float* __restrict__ acc) {
    int t = blockIdx.x * 256 + threadIdx.x;          // 0..17407
    if (t >= ACC_N) return;
    const float* p = partial + (size_t)blockIdx.y * RED_SLAB * ACC_N + t;
    float s = 0.0f;
#pragma unroll 5
    for (int k = 0; k < RED_SLAB; ++k) s += p[(size_t)k * ACC_N];
    atomicAdd(acc + t, s);
}

// Pass 3: out[b] = g_bias + cacc[b] + 0.5 * ||ev[b]||^2   (acc is plane-major)
__global__ __launch_bounds__(256) void fm_final(const float* __restrict__ acc,
                                                const float* __restrict__ g_bias,
                                                float* __restrict__ out) {
    int row = blockIdx.x * 256 + threadIdx.x;
    if (row >= B_ROWS) return;
    float s = 0.0f;
#pragma unroll
    for (int d = 0; d < D_DIM; ++d) {
        float v = acc[d * B_ROWS + row];
        s += v * v;
    }
    out[row] = g_bias[0] + acc[D_DIM * B_ROWS + row] + 0.5f * s;
}

extern "C" void kernel_launch(void* const* d_in, const int* in_sizes, int n_in,
                              void* d_out, int out_size, void* d_ws, size_t ws_size,
                              hipStream_t stream) {
    const int*   x      = (const int*)d_in[0];
    const float* emb_w  = (const float*)d_in[1];
    const float* bias_w = (const float*)d_in[2];
    const float* g_bias = (const float*)d_in[3];
    float*       out    = (float*)d_out;

    // ws layout: c[F] | acc[17*1024] | partial[625][17*1024]
    size_t c_bytes   = (size_t)F_FLD * sizeof(float);
    size_t acc_bytes = (size_t)ACC_N * sizeof(float);
    size_t par_bytes = (size_t)NCHUNK * ACC_N * sizeof(float);
    float* c       = (float*)d_ws;
    float* acc     = (float*)((char*)d_ws + c_bytes);
    float* partial = (float*)((char*)d_ws + c_bytes + acc_bytes);
    int use_partial = (ws_size >= c_bytes + acc_bytes + par_bytes) ? 1 : 0;

    fm_prep<<<dim3((F_FLD + 255) / 256), dim3(256), 0, stream>>>(emb_w, bias_w, c, acc);
    fm_main<<<dim3(NCHUNK, B_ROWS / 256), dim3(256), 0, stream>>>(
        x, emb_w, c, partial, acc, use_partial);
    if (use_partial)
        fm_reduce<<<dim3((ACC_N + 255) / 256, NCHUNK / RED_SLAB), dim3(256), 0, stream>>>(
            partial, acc);
    fm_final<<<dim3((B_ROWS + 255) / 256), dim3(256), 0, stream>>>(acc, g_bias, out);
}

// Round 4
// 858.074 us; speedup vs baseline: 1.7636x; 1.0838x over previous
//
#include <hip/hip_runtime.h>
#include <hip/hip_bf16.h>

#define B_ROWS 1024
#define F_FLD  160000
#define D_DIM  16
#define TCOLS  256                 // columns per block
#define NCHUNK (F_FLD / TCOLS)     // 625
#define NKB    (F_FLD / 32)        // 5000 K-blocks of 32 cols
#define NSTAT  (D_DIM + 1)         // 16 ev + cacc
#define ACC_N  (B_ROWS * NSTAT)    // 17408
#define RED_SLAB 25                // 625 = 25 * 25

typedef __attribute__((ext_vector_type(8))) short bf16x8;
typedef __attribute__((ext_vector_type(4))) float f32x4;

static __device__ inline unsigned short f2bf(float x) {
    __hip_bfloat16 h = __float2bfloat16(x);
    union { __hip_bfloat16 h; unsigned short s; } u; u.h = h; return u.s;
}

// Expand 8 mask bits -> 8 bf16 (1.0 / 0.0) in A-fragment register order
// (element j = bit j; dword j/2: lo half = even j, hi half = odd j).
static __device__ inline bf16x8 expand8(unsigned b) {
    union { unsigned u[4]; bf16x8 v; } r;
    r.u[0] = ((b        & 1u) * 0x3F80u) | (((b >> 1) & 1u) * 0x3F800000u);
    r.u[1] = (((b >> 2) & 1u) * 0x3F80u) | (((b >> 3) & 1u) * 0x3F800000u);
    r.u[2] = (((b >> 4) & 1u) * 0x3F80u) | (((b >> 5) & 1u) * 0x3F800000u);
    r.u[3] = (((b >> 6) & 1u) * 0x3F80u) | (((b >> 7) & 1u) * 0x3F800000u);
    return r.v;
}

// Pass 1: c[f] = bias[f] - 0.5 * ||emb[f]||^2 (f32); zero acc.
__global__ __launch_bounds__(256) void fm_prep(const float* __restrict__ emb,
                                               const float* __restrict__ bias,
                                               float* __restrict__ c,
                                               float* __restrict__ acc) {
    int i = blockIdx.x * 256 + threadIdx.x;
    if (i < F_FLD) {
        const float4* e = (const float4*)(emb + (size_t)i * D_DIM);
        float4 e0 = e[0], e1 = e[1], e2 = e[2], e3 = e[3];
        float s = e0.x*e0.x + e0.y*e0.y + e0.z*e0.z + e0.w*e0.w
                + e1.x*e1.x + e1.y*e1.y + e1.z*e1.z + e1.w*e1.w
                + e2.x*e2.x + e2.y*e2.y + e2.z*e2.z + e2.w*e2.w
                + e3.x*e3.x + e3.y*e3.y + e3.z*e3.z + e3.w*e3.w;
        c[i] = bias[i] - 0.5f * s;
    }
    if (i < ACC_N) acc[i] = 0.0f;
}

// Pass 1b: pre-pack emb (and c) into MFMA B-fragment order, bf16.
// K-block kb covers cols kb*32 + (4j + q), q = lane>>4, j = 0..7 — this
// matches the ballot-interleaved A bit order (bit 8s+j of word q).
// embB[kb][lane][j] = emb[kb*32 + 4j + q][lane&15]
// cB2c[kb][q][j]    = c  [kb*32 + 4j + q]   (broadcast B: all N cols equal)
__global__ __launch_bounds__(256) void fm_pack(const float* __restrict__ emb,
                                               const float* __restrict__ c,
                                               unsigned short* __restrict__ embB,
                                               unsigned short* __restrict__ cB2c) {
    const int tid = threadIdx.x;
    const int kb = blockIdx.x * 4 + (tid >> 6);
    const int l = tid & 63, q = l >> 4, n = l & 15;
    union { unsigned short s[8]; uint4 u; } v;
#pragma unroll
    for (int j = 0; j < 8; ++j) {
        int f = kb * 32 + 4 * j + q;
        v.s[j] = f2bf(emb[(size_t)f * D_DIM + n]);
    }
    *(uint4*)(embB + ((size_t)kb * 64 + l) * 8) = v.u;
    if (n == 0) {
        union { unsigned short s[8]; uint4 u; } w;
#pragma unroll
        for (int j = 0; j < 8; ++j) w.s[j] = f2bf(c[kb * 32 + 4 * j + q]);
        *(uint4*)(cB2c + ((size_t)kb * 4 + q) * 8) = w.u;
    }
}

// Pass 2: stream x -> ballot bitmasks -> MFMA.
// Wave w stages ONLY its own 64 rows (no __syncthreads anywhere), then runs
// 4 M-tiles x 8 K-steps x 2 MFMAs (ev GEMM + broadcast-c GEMM).
__global__ __launch_bounds__(256) void fm_main(const int* __restrict__ x,
                                               const unsigned short* __restrict__ embB,
                                               const unsigned short* __restrict__ cB2c,
                                               float* __restrict__ partial,
                                               float* __restrict__ acc,
                                               int use_partial) {
    __shared__ unsigned long long msk[256][4];
    const int tid = threadIdx.x;
    const int w = tid >> 6, l = tid & 63;
    const int q = l >> 4, n = l & 15;
    const int rowbase = blockIdx.y * 256;
    const int c0 = blockIdx.x * TCOLS;
    const int kb0 = blockIdx.x * 8;

    // ---- stage: 64 rows, int4 per lane (cols c0+4l..+3), 8-deep batches
    {
        const int4* xp = (const int4*)(x + (size_t)(rowbase + w * 64) * F_FLD + c0) + l;
        const size_t rstr = F_FLD / 4;
        for (int i = 0; i < 64; i += 8) {
            int4 v[8];
#pragma unroll
            for (int k = 0; k < 8; ++k) v[k] = xp[(size_t)(i + k) * rstr];
#pragma unroll
            for (int k = 0; k < 8; ++k) {
                unsigned long long m0 = __ballot(v[k].x > 0);  // bit i = col 4i+0
                unsigned long long m1 = __ballot(v[k].y > 0);
                unsigned long long m2 = __ballot(v[k].z > 0);
                unsigned long long m3 = __ballot(v[k].w > 0);
                if (l == 0) {
                    int r = w * 64 + i + k;
                    msk[r][0] = m0; msk[r][1] = m1; msk[r][2] = m2; msk[r][3] = m3;
                }
            }
        }
    }

    // ---- A-words: lane needs word q of its 4 M-tile rows (own wave's rows)
    unsigned long long wq[4];
#pragma unroll
    for (int mt = 0; mt < 4; ++mt) wq[mt] = msk[w * 64 + mt * 16 + n][q];

    f32x4 aev[4], ac[4];
#pragma unroll
    for (int mt = 0; mt < 4; ++mt) {
        aev[mt] = (f32x4){0.f, 0.f, 0.f, 0.f};
        ac[mt]  = (f32x4){0.f, 0.f, 0.f, 0.f};
    }

    const uint4* eB = (const uint4*)embB;
    const uint4* cB = (const uint4*)cB2c;
#pragma unroll
    for (int s = 0; s < 8; ++s) {
        union { uint4 u; bf16x8 v; } Bf, Cf;
        Bf.u = eB[(size_t)(kb0 + s) * 64 + l];
        Cf.u = cB[(size_t)(kb0 + s) * 4 + q];
#pragma unroll
        for (int mt = 0; mt < 4; ++mt) {
            unsigned b = (unsigned)(wq[mt] >> (8 * s)) & 0xFFu;
            bf16x8 A = expand8(b);
            aev[mt] = __builtin_amdgcn_mfma_f32_16x16x32_bf16(A, Bf.v, aev[mt], 0, 0, 0);
            ac[mt]  = __builtin_amdgcn_mfma_f32_16x16x32_bf16(A, Cf.v, ac[mt], 0, 0, 0);
        }
    }

    // ---- epilogue: C/D layout row = q*4 + r, col = n
    const int ch = blockIdx.x;
#pragma unroll
    for (int mt = 0; mt < 4; ++mt) {
        int rowg = rowbase + w * 64 + mt * 16 + q * 4;
        if (use_partial) {
#pragma unroll
            for (int r = 0; r < 4; ++r) {
                float* p = partial + ((size_t)ch * B_ROWS + rowg + r) * NSTAT;
                p[n] = aev[mt][r];
                if (n == 0) p[16] = ac[mt][r];
            }
        } else {
#pragma unroll
            for (int r = 0; r < 4; ++r) {
                atomicAdd(acc + (size_t)(rowg + r) * NSTAT + n, aev[mt][r]);
                if (n == 0) atomicAdd(acc + (size_t)(rowg + r) * NSTAT + 16, ac[mt][r]);
            }
        }
    }
}

// Pass 2b: fold 625 chunk-partials into acc[row][17].
__global__ __launch_bounds__(256) void fm_reduce(const float* __restrict__ partial,
                                                 float* __restrict__ acc) {
    int t = blockIdx.x * 256 + threadIdx.x;
    if (t >= ACC_N) return;
    const float* p = partial + (size_t)blockIdx.y * RED_SLAB * ACC_N + t;
    float s = 0.0f;
#pragma unroll 5
    for (int k = 0; k < RED_SLAB; ++k) s += p[(size_t)k * ACC_N];
    atomicAdd(acc + t, s);
}

// Pass 3: out[b] = g_bias + cacc[b] + 0.5 * ||ev[b]||^2
__global__ __launch_bounds__(256) void fm_final(const float* __restrict__ acc,
                                                const float* __restrict__ g_bias,
                                                float* __restrict__ out) {
    int row = blockIdx.x * 256 + threadIdx.x;
    if (row >= B_ROWS) return;
    const float* a = acc + (size_t)row * NSTAT;
    float s = 0.0f;
#pragma unroll
    for (int d = 0; d < D_DIM; ++d) s += a[d] * a[d];
    out[row] = g_bias[0] + a[16] + 0.5f * s;
}

extern "C" void kernel_launch(void* const* d_in, const int* in_sizes, int n_in,
                              void* d_out, int out_size, void* d_ws, size_t ws_size,
                              hipStream_t stream) {
    const int*   x      = (const int*)d_in[0];
    const float* emb_w  = (const float*)d_in[1];
    const float* bias_w = (const float*)d_in[2];
    const float* g_bias = (const float*)d_in[3];
    float*       out    = (float*)d_out;

    // ws layout (16B-aligned): c | acc | embB | cB2c | partial
    size_t off_c    = 0;
    size_t off_acc  = off_c   + (size_t)F_FLD * 4;            //   640,000
    size_t off_embB = off_acc + (size_t)ACC_N * 4;            //   709,632
    size_t off_cB   = off_embB + (size_t)NKB * 64 * 8 * 2;    // 5,829,632
    size_t off_par  = off_cB  + (size_t)NKB * 4 * 8 * 2;      // 6,149,632
    size_t total    = off_par + (size_t)NCHUNK * B_ROWS * NSTAT * 4;

    float*          c       = (float*)((char*)d_ws + off_c);
    float*          acc     = (float*)((char*)d_ws + off_acc);
    unsigned short* embB    = (unsigned short*)((char*)d_ws + off_embB);
    unsigned short* cB2c    = (unsigned short*)((char*)d_ws + off_cB);
    float*          partial = (float*)((char*)d_ws + off_par);
    int use_partial = (ws_size >= total) ? 1 : 0;

    fm_prep<<<dim3((F_FLD + 255) / 256), dim3(256), 0, stream>>>(emb_w, bias_w, c, acc);
    fm_pack<<<dim3(NKB / 4), dim3(256), 0, stream>>>(emb_w, c, embB, cB2c);
    fm_main<<<dim3(NCHUNK, B_ROWS / 256), dim3(256), 0, stream>>>(
        x, embB, cB2c, partial, acc, use_partial);
    if (use_partial)
        fm_reduce<<<dim3((ACC_N + 255) / 256, NCHUNK / RED_SLAB), dim3(256), 0, stream>>>(
            partial, acc);
    fm_final<<<dim3((B_ROWS + 255) / 256), dim3(256), 0, stream>>>(acc, g_bias, out);
}

// Round 5
// 851.047 us; speedup vs baseline: 1.7782x; 1.0083x over previous
//
#include <hip/hip_runtime.h>
#include <hip/hip_bf16.h>

#define B_ROWS 1024
#define F_FLD  160000
#define D_DIM  16
#define NKB    (F_FLD / 32)        // 5000 K-blocks of 32 cols
#define NSTAT  (D_DIM + 1)         // 16 ev + cacc
#define ACC_N  (B_ROWS * NSTAT)    // 17408
#define CCOLS  6400                // cols per block chunk
#define NGRP   (CCOLS / 256)       // 25 ballot groups per chunk
#define KBC    (CCOLS / 32)        // 200 K-blocks per chunk
#define NCHUNK (F_FLD / CCOLS)     // 25
#define ROWS_B 16                  // rows per block
#define WAVES  8                   // 512 threads

typedef __attribute__((ext_vector_type(8))) short bf16x8;
typedef __attribute__((ext_vector_type(4))) float f32x4;

static __device__ inline unsigned short f2bf(float x) {
    __hip_bfloat16 h = __float2bfloat16(x);
    union { __hip_bfloat16 h; unsigned short s; } u; u.h = h; return u.s;
}

// Expand 8 mask bits -> 8 bf16 (1.0/0.0) in A-fragment register order.
// (verbatim from R4, which passed with absmax = bf16 noise)
static __device__ inline bf16x8 expand8(unsigned b) {
    union { unsigned u[4]; bf16x8 v; } r;
    r.u[0] = ((b        & 1u) * 0x3F80u) | (((b >> 1) & 1u) * 0x3F800000u);
    r.u[1] = (((b >> 2) & 1u) * 0x3F80u) | (((b >> 3) & 1u) * 0x3F800000u);
    r.u[2] = (((b >> 4) & 1u) * 0x3F80u) | (((b >> 5) & 1u) * 0x3F800000u);
    r.u[3] = (((b >> 6) & 1u) * 0x3F80u) | (((b >> 7) & 1u) * 0x3F800000u);
    return r.v;
}

// Pack emb -> B-frag bf16 (embB[kb][lane][j] = emb[kb*32+4j+q][n], q=lane>>4,
// n=lane&15) and c -> broadcast-B (cB2c[kb][q][j] = bias[f]-0.5||emb[f]||^2,
// f=kb*32+4j+q), computing the row norms in-register via 16-lane butterfly.
// Also zeroes acc (ws is poisoned 0xAA every call).
__global__ __launch_bounds__(256) void fm_pack(const float* __restrict__ emb,
                                               const float* __restrict__ bias,
                                               unsigned short* __restrict__ embB,
                                               unsigned short* __restrict__ cB2c,
                                               float* __restrict__ acc) {
    const int tid = threadIdx.x;
    const int kb = blockIdx.x * 4 + (tid >> 6);
    const int l = tid & 63, q = l >> 4, n = l & 15;

    float e[8];
    union { unsigned short s[8]; uint4 u; } v;
#pragma unroll
    for (int j = 0; j < 8; ++j) {
        int f = kb * 32 + 4 * j + q;
        e[j] = emb[(size_t)f * D_DIM + n];
        v.s[j] = f2bf(e[j]);
    }
    *(uint4*)(embB + ((size_t)kb * 64 + l) * 8) = v.u;

    union { unsigned short s[8]; uint4 u; } w;
#pragma unroll
    for (int j = 0; j < 8; ++j) {
        float s = e[j] * e[j];                    // reduce over n (16 lanes)
        s += __shfl_xor(s, 1);
        s += __shfl_xor(s, 2);
        s += __shfl_xor(s, 4);
        s += __shfl_xor(s, 8);
        int f = kb * 32 + 4 * j + q;
        w.s[j] = f2bf((n == 0 ? bias[f] : 0.0f) - 0.5f * s);
    }
    if (n == 0) *(uint4*)(cB2c + ((size_t)kb * 4 + q) * 8) = w.u;

    int gid = blockIdx.x * 256 + tid;
    if (gid < ACC_N) acc[gid] = 0.0f;
}

// Main: block = 16 rows x 6400 cols. Each wave streams its 2 rows
// SEQUENTIALLY (25 contiguous 1KB wave-loads per row, 5-deep batches) ->
// ballot masks in LDS. One barrier. Waves split 200 K-blocks, 2 MFMAs each
// (ev GEMM + broadcast-c GEMM). LDS tree-reduce 8 partials -> global atomics.
__global__ __launch_bounds__(512, 6) void fm_main(const int* __restrict__ x,
                                                  const unsigned short* __restrict__ embB,
                                                  const unsigned short* __restrict__ cB2c,
                                                  float* __restrict__ acc) {
    __shared__ unsigned long long msk[NGRP][ROWS_B][4];   // 12.8 KB
    __shared__ float red[WAVES][ROWS_B][NSTAT];           //  8.7 KB

    const int tid = threadIdx.x;
    const int w = tid >> 6, l = tid & 63;
    const int q = l >> 4, n = l & 15;
    const int rowbase = blockIdx.y * ROWS_B;
    const int c0 = blockIdx.x * CCOLS;

    // ---- stage: wave w -> rows 2w, 2w+1; each row read as one sequential
    // 25.6 KB stream (bit l of word j_w at group g <-> col g*256 + 4l + j_w)
#pragma unroll
    for (int rr = 0; rr < 2; ++rr) {
        const int rloc = 2 * w + rr;
        const int4* xp = (const int4*)(x + (size_t)(rowbase + rloc) * F_FLD + c0) + l;
        for (int g0 = 0; g0 < NGRP; g0 += 5) {
            int4 v[5];
#pragma unroll
            for (int k = 0; k < 5; ++k) v[k] = xp[(size_t)(g0 + k) * 64];
#pragma unroll
            for (int k = 0; k < 5; ++k) {
                unsigned long long m0 = __ballot(v[k].x > 0);
                unsigned long long m1 = __ballot(v[k].y > 0);
                unsigned long long m2 = __ballot(v[k].z > 0);
                unsigned long long m3 = __ballot(v[k].w > 0);
                if (l == 0) {
                    msk[g0 + k][rloc][0] = m0; msk[g0 + k][rloc][1] = m1;
                    msk[g0 + k][rloc][2] = m2; msk[g0 + k][rloc][3] = m3;
                }
            }
        }
    }
    __syncthreads();

    // ---- compute: wave w owns K-blocks w*25 .. w*25+24
    f32x4 aev = {0.f, 0.f, 0.f, 0.f}, ac = {0.f, 0.f, 0.f, 0.f};
    const uint4* eB = (const uint4*)embB;
    const uint4* cB = (const uint4*)cB2c;
    const int kbg0 = blockIdx.x * KBC;

#pragma unroll 2
    for (int t = 0; t < KBC / WAVES; ++t) {
        const int kb = w * (KBC / WAVES) + t;        // 0..199 within chunk
        const int g = kb >> 3, byt = kb & 7;
        // A byte: bits j of byte `byt` of word q, row n  (verified mapping:
        // col kb*32 + 4j + q  ==  bit (byt*8+j) of word q at group g)
        unsigned long long mv = msk[g][n][q];
        unsigned b = (unsigned)(mv >> (8 * byt)) & 0xFFu;
        bf16x8 A = expand8(b);
        union { uint4 u; bf16x8 v; } Bf, Cf;
        Bf.u = eB[(size_t)(kbg0 + kb) * 64 + l];
        Cf.u = cB[(size_t)(kbg0 + kb) * 4 + q];
        aev = __builtin_amdgcn_mfma_f32_16x16x32_bf16(A, Bf.v, aev, 0, 0, 0);
        ac  = __builtin_amdgcn_mfma_f32_16x16x32_bf16(A, Cf.v, ac,  0, 0, 0);
    }

    // ---- reduce 8 wave-partials (C/D layout: row = q*4+r, col = n)
#pragma unroll
    for (int r = 0; r < 4; ++r) {
        red[w][q * 4 + r][n] = aev[r];
        if (n == 0) red[w][q * 4 + r][16] = ac[r];
    }
    __syncthreads();

    if (tid < ROWS_B * NSTAT) {
        int row = tid / NSTAT, col = tid % NSTAT;
        float s = 0.0f;
#pragma unroll
        for (int ww = 0; ww < WAVES; ++ww) s += red[ww][row][col];
        atomicAdd(acc + (size_t)(rowbase + row) * NSTAT + col, s);
    }
}

// out[b] = g_bias + cacc[b] + 0.5 * ||ev[b]||^2
__global__ __launch_bounds__(256) void fm_final(const float* __restrict__ acc,
                                                const float* __restrict__ g_bias,
                                                float* __restrict__ out) {
    int row = blockIdx.x * 256 + threadIdx.x;
    if (row >= B_ROWS) return;
    const float* a = acc + (size_t)row * NSTAT;
    float s = 0.0f;
#pragma unroll
    for (int d = 0; d < D_DIM; ++d) s += a[d] * a[d];
    out[row] = g_bias[0] + a[16] + 0.5f * s;
}

extern "C" void kernel_launch(void* const* d_in, const int* in_sizes, int n_in,
                              void* d_out, int out_size, void* d_ws, size_t ws_size,
                              hipStream_t stream) {
    const int*   x      = (const int*)d_in[0];
    const float* emb_w  = (const float*)d_in[1];
    const float* bias_w = (const float*)d_in[2];
    const float* g_bias = (const float*)d_in[3];
    float*       out    = (float*)d_out;

    // ws: embB (5,120,000 B) | cB2c (320,000 B) | acc (69,632 B)
    unsigned short* embB = (unsigned short*)d_ws;
    unsigned short* cB2c = (unsigned short*)((char*)d_ws + (size_t)NKB * 64 * 8 * 2);
    float*          acc  = (float*)((char*)d_ws + (size_t)NKB * 64 * 8 * 2
                                                + (size_t)NKB * 4 * 8 * 2);

    fm_pack<<<dim3(NKB / 4), dim3(256), 0, stream>>>(emb_w, bias_w, embB, cB2c, acc);
    fm_main<<<dim3(NCHUNK, B_ROWS / ROWS_B), dim3(512), 0, stream>>>(x, embB, cB2c, acc);
    fm_final<<<dim3((B_ROWS + 255) / 256), dim3(256), 0, stream>>>(acc, g_bias, out);
}